// Round 1
// baseline (446.682 us; speedup 1.0000x reference)
//
#include <hip/hip_runtime.h>
#include <math.h>

// ---------------------------------------------------------------------------
// CNE: 2-layer GCN (PyG GCNConv norm w/ self loops) + outcome/propensity heads
// N=100000, E=1600000, IN=128, H=64, T=C=20000. All fp32.
//
// Strategy:
//  - Build CSR by dst (histogram -> 2-level scan -> scatter). No float atomics.
//  - GEMM epilogue writes g = dinv * (X @ W); aggregation per node:
//       out[i] = act(b + dinv[i] * (g[i] + sum_{src in in(i)} g[src]))
//  - Wave-per-row kernels: W column held in per-lane VGPRs, x row read via
//    wave-uniform (readfirstlane) scalar loads.
// ---------------------------------------------------------------------------

__device__ __forceinline__ float wave_sum64(float v) {
#pragma unroll
  for (int m = 32; m >= 1; m >>= 1) v += __shfl_xor(v, m, 64);
  return v;
}

__device__ __forceinline__ float lrelu(float x) { return x > 0.0f ? x : 0.01f * x; }

// ---- degree histogram over dst ----
__global__ void k_hist(const int* __restrict__ dst, int E, int* __restrict__ count) {
  int e = blockIdx.x * blockDim.x + threadIdx.x;
  if (e < E) atomicAdd(&count[dst[e]], 1);
}

// ---- dinv = (indeg+1)^-1/2 ----
__global__ void k_dinv(const int* __restrict__ count, float* __restrict__ dinv, int N) {
  int i = blockIdx.x * blockDim.x + threadIdx.x;
  if (i < N) dinv[i] = 1.0f / sqrtf((float)(count[i] + 1));
}

// ---- scan pass B: per-256-chunk sums + exclusive scan of chunk sums ----
__global__ void k_scanB(const int* __restrict__ count, int* __restrict__ chunkbase,
                        int N, int nchunk) {
  __shared__ int s[512];
  int t = threadIdx.x;  // 512 threads
  int sum = 0;
  int base = t * 256;
  if (t < nchunk) {
    int end = min(base + 256, N);
    for (int i = base; i < end; i++) sum += count[i];
  }
  s[t] = sum;
  __syncthreads();
  for (int off = 1; off < 512; off <<= 1) {
    int v = (t >= off) ? s[t - off] : 0;
    __syncthreads();
    s[t] += v;
    __syncthreads();
  }
  chunkbase[t] = s[t] - sum;  // exclusive
}

// ---- scan pass C: intra-chunk exclusive scan -> per-node offsets ----
__global__ void k_scanC(const int* __restrict__ count, const int* __restrict__ chunkbase,
                        int* __restrict__ offs, int N) {
  __shared__ int s[256];
  int t = threadIdx.x;
  int i = blockIdx.x * 256 + t;
  int v = (i < N) ? count[i] : 0;
  s[t] = v;
  __syncthreads();
  for (int off = 1; off < 256; off <<= 1) {
    int u = (t >= off) ? s[t - off] : 0;
    __syncthreads();
    s[t] += u;
    __syncthreads();
  }
  if (i < N) offs[i] = chunkbase[blockIdx.x] + s[t] - v;
}

// ---- scatter edges into CSR slots ----
__global__ void k_scatter(const int* __restrict__ src, const int* __restrict__ dst, int E,
                          const int* __restrict__ offs, int* __restrict__ cursor,
                          int* __restrict__ slot) {
  int e = blockIdx.x * blockDim.x + threadIdx.x;
  if (e < E) {
    int d = dst[e];
    int p = atomicAdd(&cursor[d], 1);
    slot[offs[d] + p] = src[e];
  }
}

// ---- G = dinv * (X @ W)   X:[N,K] W:[K,64] ----
template <int K>
__launch_bounds__(256)
__global__ void k_gemm_scale(const float* __restrict__ X, const float* __restrict__ W,
                             const float* __restrict__ dinv, float* __restrict__ G, int N) {
  int lane = threadIdx.x & 63;
  float w[K];
#pragma unroll
  for (int k = 0; k < K; k++) w[k] = W[k * 64 + lane];
  int wid = (blockIdx.x * blockDim.x + threadIdx.x) >> 6;
  int nwave = (gridDim.x * blockDim.x) >> 6;
  for (int row = wid; row < N; row += nwave) {
    int r = __builtin_amdgcn_readfirstlane(row);
    const float4* xr = (const float4*)(X + (size_t)r * K);
    float a0 = 0.f, a1 = 0.f, a2 = 0.f, a3 = 0.f;
#pragma unroll
    for (int k = 0; k < K / 4; k++) {
      float4 xv = xr[k];
      a0 = fmaf(xv.x, w[4 * k + 0], a0);
      a1 = fmaf(xv.y, w[4 * k + 1], a1);
      a2 = fmaf(xv.z, w[4 * k + 2], a2);
      a3 = fmaf(xv.w, w[4 * k + 3], a3);
    }
    G[(size_t)r * 64 + lane] = (a0 + a1 + a2 + a3) * dinv[r];
  }
}

// ---- aggregation: Out[i] = act(bias + dinv[i]*(G[i] + sum_nbr G[src])) ----
__global__ void k_agg(const float* __restrict__ G, const int* __restrict__ offs,
                      const int* __restrict__ count, const int* __restrict__ slot,
                      const float* __restrict__ dinv, const float* __restrict__ bias,
                      float* __restrict__ Out, int N, int do_relu) {
  int lane = threadIdx.x & 63;
  int wid = (blockIdx.x * blockDim.x + threadIdx.x) >> 6;
  if (wid >= N) return;
  int r = __builtin_amdgcn_readfirstlane(wid);
  int start = offs[r], cnt = count[r];
  float acc = G[(size_t)r * 64 + lane];
  int j = 0;
  for (; j + 4 <= cnt; j += 4) {
    int s0 = slot[start + j + 0];
    int s1 = slot[start + j + 1];
    int s2 = slot[start + j + 2];
    int s3 = slot[start + j + 3];
    float a0 = G[(size_t)s0 * 64 + lane];
    float a1 = G[(size_t)s1 * 64 + lane];
    float a2 = G[(size_t)s2 * 64 + lane];
    float a3 = G[(size_t)s3 * 64 + lane];
    acc += a0 + a1 + a2 + a3;
  }
  for (; j < cnt; j++) {
    int s = slot[start + j];
    acc += G[(size_t)s * 64 + lane];
  }
  float v = bias[lane] + dinv[r] * acc;
  if (do_relu) v = fmaxf(v, 0.0f);
  Out[(size_t)r * 64 + lane] = v;
}

// ---- outcome heads: y1/yc0 (treated), y0/yc1 (control) ----
__global__ void k_heads(const float* __restrict__ Z, const int* __restrict__ treat,
                        const int* __restrict__ ctrl, int T, int C,
                        const float* __restrict__ Wy1, const float* __restrict__ by1,
                        const float* __restrict__ Wy0, const float* __restrict__ by0,
                        float* __restrict__ y1, float* __restrict__ yc0,
                        float* __restrict__ y0, float* __restrict__ yc1) {
  int lane = threadIdx.x & 63;
  int wid = (blockIdx.x * blockDim.x + threadIdx.x) >> 6;
  if (wid >= T + C) return;
  bool treated = wid < T;
  int idx = treated ? wid : wid - T;
  int row = treated ? treat[idx] : ctrl[idx];
  row = __builtin_amdgcn_readfirstlane(row);
  float v = Z[(size_t)row * 64 + lane];
  float s1 = wave_sum64(v * Wy1[lane]);
  float s0 = wave_sum64(v * Wy0[lane]);
  if (lane == 0) {
    float a1 = lrelu(s1 + by1[0]);
    float a0 = lrelu(s0 + by0[0]);
    if (treated) { y1[idx] = a1; yc0[idx] = a0; }
    else         { yc1[idx] = a1; y0[idx] = a0; }
  }
}

// ---- propensity head: tprob = lrelu(lrelu(Z@Wp1+bp1)@Wp2+bp2) ----
__launch_bounds__(256)
__global__ void k_tprob(const float* __restrict__ Z, const float* __restrict__ Wp1,
                        const float* __restrict__ bp1, const float* __restrict__ Wp2,
                        const float* __restrict__ bp2, float* __restrict__ tprob, int N) {
  int lane = threadIdx.x & 63;
  float w[64];
#pragma unroll
  for (int k = 0; k < 64; k++) w[k] = Wp1[k * 64 + lane];
  float wp2a = Wp2[lane * 2 + 0], wp2b = Wp2[lane * 2 + 1];
  float b1l = bp1[lane];
  float b20 = bp2[0], b21 = bp2[1];
  int wid = (blockIdx.x * blockDim.x + threadIdx.x) >> 6;
  int nwave = (gridDim.x * blockDim.x) >> 6;
  for (int row = wid; row < N; row += nwave) {
    int r = __builtin_amdgcn_readfirstlane(row);
    const float4* zr = (const float4*)(Z + (size_t)r * 64);
    float a0 = 0.f, a1 = 0.f, a2 = 0.f, a3 = 0.f;
#pragma unroll
    for (int k = 0; k < 16; k++) {
      float4 xv = zr[k];
      a0 = fmaf(xv.x, w[4 * k + 0], a0);
      a1 = fmaf(xv.y, w[4 * k + 1], a1);
      a2 = fmaf(xv.z, w[4 * k + 2], a2);
      a3 = fmaf(xv.w, w[4 * k + 3], a3);
    }
    float hp = lrelu(b1l + a0 + a1 + a2 + a3);
    float s0 = wave_sum64(hp * wp2a);
    float s1 = wave_sum64(hp * wp2b);
    if (lane == 0) {
      tprob[(size_t)r * 2 + 0] = lrelu(s0 + b20);
      tprob[(size_t)r * 2 + 1] = lrelu(s1 + b21);
    }
  }
}

extern "C" void kernel_launch(void* const* d_in, const int* in_sizes, int n_in,
                              void* d_out, int out_size, void* d_ws, size_t ws_size,
                              hipStream_t stream) {
  const int IN = 128, H = 64;
  const int N = in_sizes[0] / IN;
  const int E = in_sizes[1] / 2;
  const int T = in_sizes[2];
  const int C = in_sizes[3];

  const float* x    = (const float*)d_in[0];
  const int*   ei   = (const int*)d_in[1];
  const int*   src  = ei;
  const int*   dst  = ei + E;
  const int*   trt  = (const int*)d_in[2];
  const int*   ctl  = (const int*)d_in[3];
  const float* W1   = (const float*)d_in[4];
  const float* b1   = (const float*)d_in[5];
  const float* W2   = (const float*)d_in[6];
  const float* b2   = (const float*)d_in[7];
  const float* Wy1  = (const float*)d_in[8];
  const float* by1  = (const float*)d_in[9];
  const float* Wy0  = (const float*)d_in[10];
  const float* by0  = (const float*)d_in[11];
  const float* Wp1  = (const float*)d_in[12];
  const float* bp1  = (const float*)d_in[13];
  const float* Wp2  = (const float*)d_in[14];
  const float* bp2  = (const float*)d_in[15];

  float* out   = (float*)d_out;
  float* y1    = out;                       // [T]
  float* yc0   = out + T;                   // [T]
  float* y0    = out + 2 * T;               // [C]
  float* yc1   = out + 2 * T + C;           // [C]
  float* tprob = out + 2 * T + 2 * C;       // [N,2]
  float* xZ2   = out + 2 * T + 2 * C + 2 * N;  // [N,64]

  // workspace layout (all 4-byte elems)
  int* count     = (int*)d_ws;              // N
  int* cursor    = count + N;               // N
  int* offs      = cursor + N;              // N
  int* chunkbase = offs + N;                // 512
  int* slot      = chunkbase + 512;         // E
  float* dinv    = (float*)(slot + E);      // N
  float* g       = dinv + N;                // N*H
  float* xZ1     = g + (size_t)N * H;       // N*H

  hipMemsetAsync(count, 0, sizeof(int) * 2 * (size_t)N, stream);  // count + cursor

  const int nchunk = (N + 255) / 256;

  k_hist<<<(E + 255) / 256, 256, 0, stream>>>(dst, E, count);
  k_dinv<<<(N + 255) / 256, 256, 0, stream>>>(count, dinv, N);
  k_scanB<<<1, 512, 0, stream>>>(count, chunkbase, N, nchunk);
  k_scanC<<<nchunk, 256, 0, stream>>>(count, chunkbase, offs, N);
  k_scatter<<<(E + 255) / 256, 256, 0, stream>>>(src, dst, E, offs, cursor, slot);

  // layer 1: g = dinv*(x@W1); xZ1 = relu(b1 + dinv*(g_self + sum g))
  k_gemm_scale<128><<<1024, 256, 0, stream>>>(x, W1, dinv, g, N);
  k_agg<<<((size_t)N * 64 + 255) / 256, 256, 0, stream>>>(g, offs, count, slot, dinv, b1, xZ1, N, 1);

  // layer 2: g = dinv*(xZ1@W2); xZ2 = b2 + dinv*(g_self + sum g)
  k_gemm_scale<64><<<1024, 256, 0, stream>>>(xZ1, W2, dinv, g, N);
  k_agg<<<((size_t)N * 64 + 255) / 256, 256, 0, stream>>>(g, offs, count, slot, dinv, b2, xZ2, N, 0);

  // heads
  k_heads<<<((size_t)(T + C) * 64 + 255) / 256, 256, 0, stream>>>(
      xZ2, trt, ctl, T, C, Wy1, by1, Wy0, by0, y1, yc0, y0, yc1);
  k_tprob<<<2048, 256, 0, stream>>>(xZ2, Wp1, bp1, Wp2, bp2, tprob, N);
}